// Round 1
// baseline (809.340 us; speedup 1.0000x reference)
//
#include <hip/hip_runtime.h>
#include <math.h>

typedef unsigned short u16;
typedef __attribute__((ext_vector_type(8))) short short8;
typedef __attribute__((ext_vector_type(4))) float f32x4;

constexpr int NB = 32, NL = 577, ND = 512, NH = 8, NDK = 64, NFF = 2048;
constexpr int NTOK = NB * NL;          // 18464 tokens
constexpr int NLP  = 608;              // L padded to multiple of 32 (for PV K-dim)
constexpr int LDN  = NL * ND;          // 295424 elements per batch (whole-seq LN)

__device__ __forceinline__ u16 f2bf(float f) {
  union { float f; unsigned u; } v; v.f = f;
  unsigned r = v.u + 0x7fffu + ((v.u >> 16) & 1u);   // round-nearest-even
  return (u16)(r >> 16);
}
__device__ __forceinline__ float bf2f(u16 h) {
  union { unsigned u; float f; } v; v.u = ((unsigned)h) << 16; return v.f;
}
__device__ __forceinline__ void gload_lds16(const void* g, void* l) {
  __builtin_amdgcn_global_load_lds((const __attribute__((address_space(1))) void*)g,
                                   (__attribute__((address_space(3))) void*)l, 16, 0, 0);
}

// ---------------- whole-sequence LayerNorm ----------------
// stats: per-batch partial sums (sum, sumsq) via atomics; grid (NB, 8)
__global__ void ln_stats(const float* __restrict__ x, float* __restrict__ stats) {
  const int b = blockIdx.x, s = blockIdx.y;
  const int per4 = LDN / 8 / 4;  // 9232 float4 per split
  const float4* xb = (const float4*)(x + (size_t)b * LDN + (size_t)s * (LDN / 8));
  float sum = 0.f, ss = 0.f;
  for (int i = threadIdx.x; i < per4; i += blockDim.x) {
    float4 v = xb[i];
    sum += v.x + v.y + v.z + v.w;
    ss  += v.x * v.x + v.y * v.y + v.z * v.z + v.w * v.w;
  }
#pragma unroll
  for (int o = 32; o; o >>= 1) { sum += __shfl_down(sum, o); ss += __shfl_down(ss, o); }
  __shared__ float s0[4], s1[4];
  const int lane = threadIdx.x & 63, w = threadIdx.x >> 6;
  if (lane == 0) { s0[w] = sum; s1[w] = ss; }
  __syncthreads();
  if (threadIdx.x == 0) {
    atomicAdd(&stats[b * 2 + 0], s0[0] + s0[1] + s0[2] + s0[3]);
    atomicAdd(&stats[b * 2 + 1], s1[0] + s1[1] + s1[2] + s1[3]);
  }
}

// apply: out_bf16 = gamma*(x-mean)/(std+eps)+beta ; std is unbiased (ddof=1)
__global__ void ln_apply(const float* __restrict__ x, const float* __restrict__ stats,
                         const float* __restrict__ gamma, const float* __restrict__ beta,
                         u16* __restrict__ out) {
  const int nv = LDN / 4;  // 73856 float4 per batch
  const size_t total = (size_t)NB * nv;
  for (size_t i = (size_t)blockIdx.x * blockDim.x + threadIdx.x; i < total;
       i += (size_t)gridDim.x * blockDim.x) {
    const int b = (int)(i / nv);
    const int j = (int)(i - (size_t)b * nv);
    const float sum = stats[b * 2], ssum = stats[b * 2 + 1];
    const float mean = sum / (float)LDN;
    const float var = (ssum - (float)LDN * mean * mean) / (float)(LDN - 1);
    const float inv = 1.0f / (sqrtf(var) + 1e-6f);
    const float4 xv = ((const float4*)x)[i];
    const float4 gv = ((const float4*)gamma)[j];
    const float4 bv = ((const float4*)beta)[j];
    ushort4 o;
    o.x = f2bf(gv.x * ((xv.x - mean) * inv) + bv.x);
    o.y = f2bf(gv.y * ((xv.y - mean) * inv) + bv.y);
    o.z = f2bf(gv.z * ((xv.z - mean) * inv) + bv.z);
    o.w = f2bf(gv.w * ((xv.w - mean) * inv) + bv.w);
    ((ushort4*)out)[i] = o;
  }
}

// ---------------- weight transpose fp32[K][N] -> bf16[N][K] ----------------
__global__ void transpose_bf16(const float* __restrict__ w, u16* __restrict__ wt,
                               int K, int N) {
  const size_t total = (size_t)K * N;
  for (size_t i = (size_t)blockIdx.x * blockDim.x + threadIdx.x; i < total;
       i += (size_t)gridDim.x * blockDim.x) {
    const int k = (int)(i / N), n = (int)(i - (size_t)k * N);
    wt[(size_t)n * K + k] = f2bf(w[i]);
  }
}

// ---------------- row softmax in place on bf16 [rows][NLP], valid cols NL ----------------
__global__ void softmax_rows(u16* __restrict__ sc) {
  u16* row = sc + (size_t)blockIdx.x * NLP;
  const int tid = threadIdx.x;
  float v[3]; int cnt = 0; float mx = -1e30f;
  for (int i = tid; i < NL; i += 256) { v[cnt] = bf2f(row[i]); mx = fmaxf(mx, v[cnt]); cnt++; }
#pragma unroll
  for (int o = 32; o; o >>= 1) mx = fmaxf(mx, __shfl_xor(mx, o));
  __shared__ float red[4], red2[4];
  const int lane = tid & 63, w = tid >> 6;
  if (lane == 0) red[w] = mx;
  __syncthreads();
  mx = fmaxf(fmaxf(red[0], red[1]), fmaxf(red[2], red[3]));
  float sum = 0.f;
  for (int c = 0; c < cnt; c++) { v[c] = __expf(v[c] - mx); sum += v[c]; }
#pragma unroll
  for (int o = 32; o; o >>= 1) sum += __shfl_xor(sum, o);
  if (lane == 0) red2[w] = sum;
  __syncthreads();
  sum = red2[0] + red2[1] + red2[2] + red2[3];
  const float inv = 1.0f / sum;
  cnt = 0;
  for (int i = tid; i < NL; i += 256) { row[i] = f2bf(v[cnt] * inv); cnt++; }
  for (int i = NL + tid; i < NLP; i += 256) row[i] = 0;  // zero K-pad for PV
}

// ---------------- generic bf16 MFMA GEMM: C = A[M,K] @ Bt[N,K]^T ----------------
// m97-style: 128x128 tile, BK=32, 4 waves (2x2 quadrants of 64x64), global_load_lds w=16.
// EPI: 0 q/k scatter +bias  1 v scatter-transposed +bias  2 scores *1/sqrt(512)
//      3 PV gather           4 f32 out = v+bias+res        5 bf16 out = gelu(v+bias)
template <int EPI>
__global__ __launch_bounds__(256, 2) void gemm_bt(
    const u16* __restrict__ A, const u16* __restrict__ Bt,
    int M, int N, int K, int lda, int ldb,
    long sA, long sB, long sO,
    const float* __restrict__ bias,
    const float* __restrict__ res, int ldr,
    void* __restrict__ outp, int bh0) {
  __shared__ __align__(16) u16 lA[128 * 32];
  __shared__ __align__(16) u16 lB[128 * 32];
  const int tid = threadIdx.x, lane = tid & 63, wid = tid >> 6;
  const int l16 = lane & 15, l4 = lane >> 4;
  const int m0 = blockIdx.x * 128, n0 = blockIdx.y * 128;
  const int z = blockIdx.z;
  const u16* Ab = A + (size_t)z * sA;
  const u16* Bb = Bt + (size_t)z * sB;
  const int wm = wid >> 1, wn = wid & 1;

  f32x4 acc[4][4] = {};

  const int e0 = wid * 1024 + lane * 8;
  for (int k0 = 0; k0 < K; k0 += 32) {
#pragma unroll
    for (int i = 0; i < 2; i++) {
      const int e = e0 + i * 512;          // element index in the 128x32 tile
      const int row = e >> 5, kk = e & 31; // linear LDS == row-major [128][32]
      gload_lds16(Ab + (size_t)(m0 + row) * lda + (k0 + kk), &lA[wid * 1024 + i * 512]);
      gload_lds16(Bb + (size_t)(n0 + row) * ldb + (k0 + kk), &lB[wid * 1024 + i * 512]);
    }
    __syncthreads();
    short8 af[4], bfr[4];
#pragma unroll
    for (int mi = 0; mi < 4; mi++)
      af[mi] = *(const short8*)&lA[(wm * 64 + mi * 16 + l16) * 32 + l4 * 8];
#pragma unroll
    for (int ni = 0; ni < 4; ni++)
      bfr[ni] = *(const short8*)&lB[(wn * 64 + ni * 16 + l16) * 32 + l4 * 8];
#pragma unroll
    for (int mi = 0; mi < 4; mi++)
#pragma unroll
      for (int ni = 0; ni < 4; ni++)
        acc[mi][ni] = __builtin_amdgcn_mfma_f32_16x16x32_bf16(af[mi], bfr[ni], acc[mi][ni], 0, 0, 0);
    __syncthreads();
  }

  // epilogue: C/D layout col=lane&15, row=(lane>>4)*4+reg (verified m89/m91)
#pragma unroll
  for (int mi = 0; mi < 4; mi++) {
#pragma unroll
    for (int r = 0; r < 4; r++) {
      const int row = m0 + wm * 64 + mi * 16 + l4 * 4 + r;
      if (row >= M) continue;
      int rb = 0, rl = 0;
      if (EPI == 0 || EPI == 1) { rb = row / NL; rl = row - rb * NL; }
#pragma unroll
      for (int ni = 0; ni < 4; ni++) {
        const int col = n0 + wn * 64 + ni * 16 + l16;
        if (col >= N) continue;
        const float v = acc[mi][ni][r];
        if (EPI == 0) {          // q/k -> [B,H,L,DK] bf16
          const int h = col >> 6, d = col & 63;
          ((u16*)outp)[(((size_t)rb * NH + h) * NL + rl) * NDK + d] = f2bf(v + bias[col]);
        } else if (EPI == 1) {   // v -> [B,H,DK,NLP] bf16 (transposed, zero-padded cols)
          const int h = col >> 6, d = col & 63;
          ((u16*)outp)[(((size_t)rb * NH + h) * NDK + d) * NLP + rl] = f2bf(v + bias[col]);
        } else if (EPI == 2) {   // scores * 1/sqrt(D)
          ((u16*)outp)[(size_t)z * sO + (size_t)row * NLP + col] = f2bf(v * 0.04419417382415922f);
        } else if (EPI == 3) {   // PV -> attn_o [B,L,D] bf16
          const int bh = bh0 + z, b = bh >> 3, h = bh & 7;
          ((u16*)outp)[((size_t)b * NL + row) * ND + h * NDK + col] = f2bf(v);
        } else if (EPI == 4) {   // f32 out = v + bias + residual
          ((float*)outp)[(size_t)row * N + col] = v + bias[col] + res[(size_t)row * ldr + col];
        } else {                 // 5: bf16 out = gelu_exact(v + bias)
          const float t = v + bias[col];
          ((u16*)outp)[(size_t)row * N + col] =
              f2bf(0.5f * t * (1.0f + erff(t * 0.7071067811865475f)));
        }
      }
    }
  }
}

extern "C" void kernel_launch(void* const* d_in, const int* in_sizes, int n_in,
                              void* d_out, int out_size, void* d_ws, size_t ws_size,
                              hipStream_t stream) {
  const float* x      = (const float*)d_in[0];
  const float* gamma1 = (const float*)d_in[1];
  const float* beta1  = (const float*)d_in[2];
  const float* gamma2 = (const float*)d_in[3];
  const float* beta2  = (const float*)d_in[4];
  const float* wq = (const float*)d_in[5];
  const float* bq = (const float*)d_in[6];
  const float* wk = (const float*)d_in[7];
  const float* bk = (const float*)d_in[8];
  const float* wv = (const float*)d_in[9];
  const float* bv = (const float*)d_in[10];
  const float* wo = (const float*)d_in[11];
  const float* bo = (const float*)d_in[12];
  const float* w1 = (const float*)d_in[13];
  const float* b1 = (const float*)d_in[14];
  const float* w2 = (const float*)d_in[15];
  const float* b2 = (const float*)d_in[16];
  float* out = (float*)d_out;

  char* ws = (char*)d_ws;
  size_t off = 0;
  auto take = [&](size_t bytes) { size_t o = off; off += (bytes + 255) & ~(size_t)255; return o; };
  const size_t SLK = 1u << 20;  // tail slack per buffer: edge tiles may over-read

  float* stats = (float*)(ws + take(512));        // stats1 (64B used) + stats2
  float* stats1 = stats;
  float* stats2 = stats + 64;
  u16* wqT = (u16*)(ws + take((size_t)512 * 512 * 2));
  u16* wkT = (u16*)(ws + take((size_t)512 * 512 * 2));
  u16* wvT = (u16*)(ws + take((size_t)512 * 512 * 2));
  u16* woT = (u16*)(ws + take((size_t)512 * 512 * 2));
  u16* w1T = (u16*)(ws + take((size_t)512 * 2048 * 2));
  u16* w2T = (u16*)(ws + take((size_t)2048 * 512 * 2));
  float* hbuf = (float*)(ws + take((size_t)NTOK * ND * 4 + SLK));
  u16* qb = (u16*)(ws + take((size_t)NB * NH * NL * NDK * 2 + SLK));
  u16* kb = (u16*)(ws + take((size_t)NB * NH * NL * NDK * 2 + SLK));
  const size_t VTB = (size_t)NB * NH * NDK * NLP * 2;
  u16* vt = (u16*)(ws + take(VTB + SLK));
  u16* aog = (u16*)(ws + take((size_t)NTOK * ND * 2 + SLK));  // attn_o, later ln2 out (g)
  // region7: xn (pre-attn) / scores chunk (attn) / u (FFN) — lifetimes disjoint
  const size_t SC_B = (size_t)64 * NL * NLP * 2;   // 44.9 MB scores chunk
  const size_t U_B  = (size_t)NTOK * NFF * 2;      // 75.6 MB
  size_t r7 = take((U_B > SC_B ? U_B : SC_B) + SLK);
  u16* xn     = (u16*)(ws + r7);
  u16* scores = (u16*)(ws + r7);
  u16* ubuf   = (u16*)(ws + r7);

  hipMemsetAsync(stats, 0, 512, stream);
  hipMemsetAsync(vt, 0, VTB, stream);  // guarantees zero K-pad cols [577,608) for PV

  transpose_bf16<<<512, 256, 0, stream>>>(wq, wqT, 512, 512);
  transpose_bf16<<<512, 256, 0, stream>>>(wk, wkT, 512, 512);
  transpose_bf16<<<512, 256, 0, stream>>>(wv, wvT, 512, 512);
  transpose_bf16<<<512, 256, 0, stream>>>(wo, woT, 512, 512);
  transpose_bf16<<<2048, 256, 0, stream>>>(w1, w1T, 512, 2048);
  transpose_bf16<<<2048, 256, 0, stream>>>(w2, w2T, 2048, 512);

  // LN1 -> xn (bf16)
  ln_stats<<<dim3(NB, 8), 256, 0, stream>>>(x, stats1);
  ln_apply<<<2048, 256, 0, stream>>>(x, stats1, gamma1, beta1, xn);

  // Q,K,V projections
  dim3 gP((NTOK + 127) / 128, ND / 128, 1);
  gemm_bt<0><<<gP, 256, 0, stream>>>(xn, wqT, NTOK, ND, ND, ND, ND, 0, 0, 0,
                                     bq, nullptr, 0, qb, 0);
  gemm_bt<0><<<gP, 256, 0, stream>>>(xn, wkT, NTOK, ND, ND, ND, ND, 0, 0, 0,
                                     bk, nullptr, 0, kb, 0);
  gemm_bt<1><<<gP, 256, 0, stream>>>(xn, wvT, NTOK, ND, ND, ND, ND, 0, 0, 0,
                                     bv, nullptr, 0, vt, 0);

  // attention in 4 chunks of 64 (b,h) pairs; scores materialized bf16 [64][577][608]
  for (int c = 0; c < 4; c++) {
    const int bh0 = c * 64;
    gemm_bt<2><<<dim3(5, 5, 64), 256, 0, stream>>>(
        qb + (size_t)bh0 * NL * NDK, kb + (size_t)bh0 * NL * NDK,
        NL, NL, NDK, NDK, NDK,
        (long)NL * NDK, (long)NL * NDK, (long)NL * NLP,
        nullptr, nullptr, 0, scores, bh0);
    softmax_rows<<<64 * NL, 256, 0, stream>>>(scores);
    gemm_bt<3><<<dim3(5, 1, 64), 256, 0, stream>>>(
        scores, vt + (size_t)bh0 * NDK * NLP,
        NL, NDK, NLP, NLP, NLP,
        (long)NL * NLP, (long)NDK * NLP, 0,
        nullptr, nullptr, 0, aog, bh0);
  }

  // output projection + residual(x) -> hbuf (f32)
  gemm_bt<4><<<gP, 256, 0, stream>>>(aog, woT, NTOK, ND, ND, ND, ND, 0, 0, 0,
                                     bo, x, ND, hbuf, 0);

  // LN2 -> g (bf16, reuses aog)
  ln_stats<<<dim3(NB, 8), 256, 0, stream>>>(hbuf, stats2);
  ln_apply<<<2048, 256, 0, stream>>>(hbuf, stats2, gamma2, beta2, aog);

  // FFN
  gemm_bt<5><<<dim3((NTOK + 127) / 128, NFF / 128, 1), 256, 0, stream>>>(
      aog, w1T, NTOK, NFF, ND, ND, ND, 0, 0, 0, b1, nullptr, 0, ubuf, 0);
  gemm_bt<4><<<gP, 256, 0, stream>>>(ubuf, w2T, NTOK, ND, NFF, NFF, NFF, 0, 0, 0,
                                     b2, hbuf, ND, out, 0);
}

// Round 2
// 518.330 us; speedup vs baseline: 1.5614x; 1.5614x over previous
//
#include <hip/hip_runtime.h>
#include <math.h>

typedef unsigned short u16;
typedef __attribute__((ext_vector_type(8))) short short8;
typedef __attribute__((ext_vector_type(4))) float f32x4;

constexpr int NB = 32, NL = 577, ND = 512, NH = 8, NDK = 64, NFF = 2048;
constexpr int NTOK = NB * NL;          // 18464 tokens
constexpr int NLP  = 640;              // L padded (Q rows and KV rows) to mult of 128
constexpr int LDN  = NL * ND;          // 295424 elements per batch (whole-seq LN)

__device__ __forceinline__ u16 f2bf(float f) {
  union { float f; unsigned u; } v; v.f = f;
  unsigned r = v.u + 0x7fffu + ((v.u >> 16) & 1u);   // round-nearest-even
  return (u16)(r >> 16);
}
__device__ __forceinline__ float bf2f(u16 h) {
  union { unsigned u; float f; } v; v.u = ((unsigned)h) << 16; return v.f;
}
__device__ __forceinline__ void gload_lds16(const void* g, void* l) {
  __builtin_amdgcn_global_load_lds((const __attribute__((address_space(1))) void*)g,
                                   (__attribute__((address_space(3))) void*)l, 16, 0, 0);
}
// bijective XCD swizzle (m204): consecutive output ids land on one XCD
__device__ __forceinline__ int xcd_swz(int lin, int nwg) {
  const int xcd = lin & 7, o = lin >> 3;
  const int q = nwg >> 3, r = nwg & 7;
  return (xcd < r ? xcd * (q + 1) : r * (q + 1) + (xcd - r) * q) + o;
}

// ---------------- whole-sequence LayerNorm ----------------
__global__ void ln_stats(const float* __restrict__ x, float* __restrict__ stats) {
  const int b = blockIdx.x, s = blockIdx.y;
  const int per4 = LDN / 8 / 4;
  const float4* xb = (const float4*)(x + (size_t)b * LDN + (size_t)s * (LDN / 8));
  float sum = 0.f, ss = 0.f;
  for (int i = threadIdx.x; i < per4; i += blockDim.x) {
    float4 v = xb[i];
    sum += v.x + v.y + v.z + v.w;
    ss  += v.x * v.x + v.y * v.y + v.z * v.z + v.w * v.w;
  }
#pragma unroll
  for (int o = 32; o; o >>= 1) { sum += __shfl_down(sum, o); ss += __shfl_down(ss, o); }
  __shared__ float s0[4], s1[4];
  const int lane = threadIdx.x & 63, w = threadIdx.x >> 6;
  if (lane == 0) { s0[w] = sum; s1[w] = ss; }
  __syncthreads();
  if (threadIdx.x == 0) {
    atomicAdd(&stats[b * 2 + 0], s0[0] + s0[1] + s0[2] + s0[3]);
    atomicAdd(&stats[b * 2 + 1], s1[0] + s1[1] + s1[2] + s1[3]);
  }
}

__global__ void ln_apply(const float* __restrict__ x, const float* __restrict__ stats,
                         const float* __restrict__ gamma, const float* __restrict__ beta,
                         u16* __restrict__ out) {
  const int nv = LDN / 4;
  const size_t total = (size_t)NB * nv;
  for (size_t i = (size_t)blockIdx.x * blockDim.x + threadIdx.x; i < total;
       i += (size_t)gridDim.x * blockDim.x) {
    const int b = (int)(i / nv);
    const int j = (int)(i - (size_t)b * nv);
    const float sum = stats[b * 2], ssum = stats[b * 2 + 1];
    const float mean = sum / (float)LDN;
    const float var = (ssum - (float)LDN * mean * mean) / (float)(LDN - 1);
    const float inv = 1.0f / (sqrtf(var) + 1e-6f);
    const float4 xv = ((const float4*)x)[i];
    const float4 gv = ((const float4*)gamma)[j];
    const float4 bv = ((const float4*)beta)[j];
    ushort4 o;
    o.x = f2bf(gv.x * ((xv.x - mean) * inv) + bv.x);
    o.y = f2bf(gv.y * ((xv.y - mean) * inv) + bv.y);
    o.z = f2bf(gv.z * ((xv.z - mean) * inv) + bv.z);
    o.w = f2bf(gv.w * ((xv.w - mean) * inv) + bv.w);
    ((ushort4*)out)[i] = o;
  }
}

// ---------------- weight transpose fp32[K][N] -> bf16[N][K] ----------------
__global__ void transpose_bf16(const float* __restrict__ w, u16* __restrict__ wt,
                               int K, int N) {
  const size_t total = (size_t)K * N;
  for (size_t i = (size_t)blockIdx.x * blockDim.x + threadIdx.x; i < total;
       i += (size_t)gridDim.x * blockDim.x) {
    const int k = (int)(i / N), n = (int)(i - (size_t)k * N);
    wt[(size_t)n * K + k] = f2bf(w[i]);
  }
}

// ---------------- generic bf16 MFMA GEMM: C = A[M,K] @ Bt[N,K]^T ----------------
// 128x128 tile, BK=32, 4 waves, global_load_lds w=16, XCD-chunked (col-fastest).
// EPI: 0 q/k scatter +bias (pad-640 rows)  1 v scatter-transposed +bias
//      4 f32 out = v+bias+res              5 bf16 out = gelu_exact(v+bias)
template <int EPI>
__global__ __launch_bounds__(256, 2) void gemm_bt(
    const u16* __restrict__ A, const u16* __restrict__ Bt,
    int M, int N, int K, int lda, int ldb,
    const float* __restrict__ bias,
    const float* __restrict__ res, int ldr,
    void* __restrict__ outp) {
  __shared__ __align__(16) u16 lA[128 * 32];
  __shared__ __align__(16) u16 lB[128 * 32];
  int lin = blockIdx.x + blockIdx.y * gridDim.x;
  lin = xcd_swz(lin, gridDim.x * gridDim.y);
  const int bx = lin / gridDim.y, by = lin - (lin / gridDim.y) * gridDim.y;
  const int m0 = bx * 128, n0 = by * 128;
  const int tid = threadIdx.x, lane = tid & 63, wid = tid >> 6;
  const int l16 = lane & 15, l4 = lane >> 4;
  const int wm = wid >> 1, wn = wid & 1;

  f32x4 acc[4][4] = {};

  const int e0 = wid * 1024 + lane * 8;
  for (int k0 = 0; k0 < K; k0 += 32) {
#pragma unroll
    for (int i = 0; i < 2; i++) {
      const int e = e0 + i * 512;          // element index in the 128x32 tile
      const int row = e >> 5, kk = e & 31; // linear LDS == row-major [128][32]
      gload_lds16(A + (size_t)(m0 + row) * lda + (k0 + kk), &lA[wid * 1024 + i * 512]);
      gload_lds16(Bt + (size_t)(n0 + row) * ldb + (k0 + kk), &lB[wid * 1024 + i * 512]);
    }
    __syncthreads();
    short8 af[4], bfr[4];
#pragma unroll
    for (int mi = 0; mi < 4; mi++)
      af[mi] = *(const short8*)&lA[(wm * 64 + mi * 16 + l16) * 32 + l4 * 8];
#pragma unroll
    for (int ni = 0; ni < 4; ni++)
      bfr[ni] = *(const short8*)&lB[(wn * 64 + ni * 16 + l16) * 32 + l4 * 8];
#pragma unroll
    for (int mi = 0; mi < 4; mi++)
#pragma unroll
      for (int ni = 0; ni < 4; ni++)
        acc[mi][ni] = __builtin_amdgcn_mfma_f32_16x16x32_bf16(af[mi], bfr[ni], acc[mi][ni], 0, 0, 0);
    __syncthreads();
  }

  // epilogue: C/D layout col=lane&15, row=(lane>>4)*4+reg (verified m89/m91)
#pragma unroll
  for (int mi = 0; mi < 4; mi++) {
#pragma unroll
    for (int r = 0; r < 4; r++) {
      const int row = m0 + wm * 64 + mi * 16 + l4 * 4 + r;
      if (row >= M) continue;
      int rb = 0, rl = 0;
      if (EPI == 0 || EPI == 1) { rb = row / NL; rl = row - rb * NL; }
#pragma unroll
      for (int ni = 0; ni < 4; ni++) {
        const int col = n0 + wn * 64 + ni * 16 + l16;
        if (col >= N) continue;
        const float v = acc[mi][ni][r];
        if (EPI == 0) {          // q/k -> [BH][NLP][DK] bf16, rows 577..639 stay zero
          const int h = col >> 6, d = col & 63;
          ((u16*)outp)[(((size_t)rb * NH + h) * NLP + rl) * NDK + d] = f2bf(v + bias[col]);
        } else if (EPI == 1) {   // v -> [BH][DK][NLP] bf16 (transposed, cols 577.. zero)
          const int h = col >> 6, d = col & 63;
          ((u16*)outp)[(((size_t)rb * NH + h) * NDK + d) * NLP + rl] = f2bf(v + bias[col]);
        } else if (EPI == 4) {   // f32 out = v + bias + residual
          ((float*)outp)[(size_t)row * N + col] = v + bias[col] + res[(size_t)row * ldr + col];
        } else {                 // 5: bf16 out = gelu_exact(v + bias)
          const float t = v + bias[col];
          ((u16*)outp)[(size_t)row * N + col] =
              f2bf(0.5f * t * (1.0f + erff(t * 0.7071067811865475f)));
        }
      }
    }
  }
}

// ---------------- fused flash attention ----------------
// grid (5 q-tiles, 256 bh); block 256 = 4 waves x 32 Q-rows = 128 Q-rows/block.
// K/V read from global (L2-resident per-XCD via swizzle). Online softmax in regs.
// P transpose via per-wave padded LDS [32][68] (no cross-wave sync needed).
__global__ __launch_bounds__(256, 2) void attn_fused(
    const u16* __restrict__ qb, const u16* __restrict__ kb,
    const u16* __restrict__ vt, u16* __restrict__ aog) {
  __shared__ u16 pl[4][32][68];
  const int tid = threadIdx.x, lane = tid & 63, wid = tid >> 6;
  const int l16 = lane & 15, l4 = lane >> 4;
  int lin = blockIdx.x + blockIdx.y * gridDim.x;
  lin = xcd_swz(lin, gridDim.x * gridDim.y);
  const int gx = gridDim.x;
  const int qt = lin - (lin / gx) * gx;   // bx fastest: one XCD handles 32 consecutive bh
  const int bh = lin / gx;
  const int q0 = qt * 128 + wid * 32;
  const u16* Qp = qb + (size_t)bh * NLP * NDK;
  const u16* Kp = kb + (size_t)bh * NLP * NDK;
  const u16* Vp = vt + (size_t)bh * NDK * NLP;

  short8 qf[2][2];
#pragma unroll
  for (int mi = 0; mi < 2; mi++)
#pragma unroll
    for (int kc = 0; kc < 2; kc++)
      qf[mi][kc] = *(const short8*)&Qp[(size_t)(q0 + mi * 16 + l16) * NDK + kc * 32 + l4 * 8];

  f32x4 o[2][4] = {};
  float m[2][4], l[2][4];
#pragma unroll
  for (int mi = 0; mi < 2; mi++)
#pragma unroll
    for (int r = 0; r < 4; r++) { m[mi][r] = -3e38f; l[mi][r] = 0.f; }

  const float SCALE = 0.04419417382415922f;  // 1/sqrt(512)  (note: d_model, not d_k)

  for (int kv0 = 0; kv0 < NLP; kv0 += 64) {
    // ---- S = Q @ K^T for this 64-wide KV tile ----
    f32x4 s[2][4] = {};
#pragma unroll
    for (int ni = 0; ni < 4; ni++) {
      const short8 kf0 = *(const short8*)&Kp[(size_t)(kv0 + ni * 16 + l16) * NDK + l4 * 8];
      const short8 kf1 = *(const short8*)&Kp[(size_t)(kv0 + ni * 16 + l16) * NDK + 32 + l4 * 8];
#pragma unroll
      for (int mi = 0; mi < 2; mi++) {
        s[mi][ni] = __builtin_amdgcn_mfma_f32_16x16x32_bf16(qf[mi][0], kf0, s[mi][ni], 0, 0, 0);
        s[mi][ni] = __builtin_amdgcn_mfma_f32_16x16x32_bf16(qf[mi][1], kf1, s[mi][ni], 0, 0, 0);
      }
    }
    // ---- prefetch V fragments (independent of softmax VALU below) ----
    short8 vf[4][2];
#pragma unroll
    for (int nd = 0; nd < 4; nd++)
#pragma unroll
      for (int kvc = 0; kvc < 2; kvc++)
        vf[nd][kvc] = *(const short8*)&Vp[(size_t)(nd * 16 + l16) * NLP + kv0 + kvc * 32 + l4 * 8];

    // ---- scale + mask invalid kv ----
#pragma unroll
    for (int ni = 0; ni < 4; ni++) {
      const bool valid = (kv0 + ni * 16 + l16) < NL;
#pragma unroll
      for (int mi = 0; mi < 2; mi++)
#pragma unroll
        for (int r = 0; r < 4; r++)
          s[mi][ni][r] = valid ? s[mi][ni][r] * SCALE : -1e30f;
    }
    // ---- online softmax (row = l4*4+r within 16-lane group) ----
#pragma unroll
    for (int mi = 0; mi < 2; mi++) {
#pragma unroll
      for (int r = 0; r < 4; r++) {
        float t = fmaxf(fmaxf(s[mi][0][r], s[mi][1][r]), fmaxf(s[mi][2][r], s[mi][3][r]));
        t = fmaxf(t, __shfl_xor(t, 1));
        t = fmaxf(t, __shfl_xor(t, 2));
        t = fmaxf(t, __shfl_xor(t, 4));
        t = fmaxf(t, __shfl_xor(t, 8));
        const float mn = fmaxf(m[mi][r], t);
        const float sc = __expf(m[mi][r] - mn);
        m[mi][r] = mn;
        float rs = 0.f;
#pragma unroll
        for (int ni = 0; ni < 4; ni++) {
          const float p = __expf(s[mi][ni][r] - mn);
          s[mi][ni][r] = p;
          rs += p;
        }
        rs += __shfl_xor(rs, 1);
        rs += __shfl_xor(rs, 2);
        rs += __shfl_xor(rs, 4);
        rs += __shfl_xor(rs, 8);
        l[mi][r] = l[mi][r] * sc + rs;
#pragma unroll
        for (int nd = 0; nd < 4; nd++) o[mi][nd][r] *= sc;
      }
    }
    // ---- P -> LDS (per-wave, padded stride 68 u16 -> <=2-way banks) ----
#pragma unroll
    for (int mi = 0; mi < 2; mi++)
#pragma unroll
      for (int ni = 0; ni < 4; ni++)
#pragma unroll
        for (int r = 0; r < 4; r++)
          pl[wid][mi * 16 + l4 * 4 + r][ni * 16 + l16] = f2bf(s[mi][ni][r]);
    // ---- read P as A-fragments, O += P @ V ----
    short8 pa[2][2];
#pragma unroll
    for (int mi = 0; mi < 2; mi++)
#pragma unroll
      for (int kvc = 0; kvc < 2; kvc++)
        pa[mi][kvc] = *(const short8*)&pl[wid][mi * 16 + l16][kvc * 32 + l4 * 8];
#pragma unroll
    for (int mi = 0; mi < 2; mi++)
#pragma unroll
      for (int nd = 0; nd < 4; nd++) {
        o[mi][nd] = __builtin_amdgcn_mfma_f32_16x16x32_bf16(pa[mi][0], vf[nd][0], o[mi][nd], 0, 0, 0);
        o[mi][nd] = __builtin_amdgcn_mfma_f32_16x16x32_bf16(pa[mi][1], vf[nd][1], o[mi][nd], 0, 0, 0);
      }
  }

  // ---- normalize + store ----
  const int b = bh >> 3, h = bh & 7;
#pragma unroll
  for (int mi = 0; mi < 2; mi++) {
#pragma unroll
    for (int r = 0; r < 4; r++) {
      const int grow = q0 + mi * 16 + l4 * 4 + r;
      if (grow >= NL) continue;
      const float inv = 1.0f / l[mi][r];
#pragma unroll
      for (int nd = 0; nd < 4; nd++)
        aog[((size_t)b * NL + grow) * ND + h * NDK + nd * 16 + l16] = f2bf(o[mi][nd][r] * inv);
    }
  }
}

extern "C" void kernel_launch(void* const* d_in, const int* in_sizes, int n_in,
                              void* d_out, int out_size, void* d_ws, size_t ws_size,
                              hipStream_t stream) {
  const float* x      = (const float*)d_in[0];
  const float* gamma1 = (const float*)d_in[1];
  const float* beta1  = (const float*)d_in[2];
  const float* gamma2 = (const float*)d_in[3];
  const float* beta2  = (const float*)d_in[4];
  const float* wq = (const float*)d_in[5];
  const float* bq = (const float*)d_in[6];
  const float* wk = (const float*)d_in[7];
  const float* bk = (const float*)d_in[8];
  const float* wv = (const float*)d_in[9];
  const float* bv = (const float*)d_in[10];
  const float* wo = (const float*)d_in[11];
  const float* bo = (const float*)d_in[12];
  const float* w1 = (const float*)d_in[13];
  const float* b1 = (const float*)d_in[14];
  const float* w2 = (const float*)d_in[15];
  const float* b2 = (const float*)d_in[16];
  float* out = (float*)d_out;

  char* ws = (char*)d_ws;
  size_t off = 0;
  auto take = [&](size_t bytes) { size_t o = off; off += (bytes + 255) & ~(size_t)255; return o; };
  const size_t SLK = 1u << 20;  // tail slack per buffer: edge tiles may over-read

  float* stats = (float*)(ws + take(512));
  float* stats1 = stats;
  float* stats2 = stats + 64;
  u16* wqT = (u16*)(ws + take((size_t)512 * 512 * 2));
  u16* wkT = (u16*)(ws + take((size_t)512 * 512 * 2));
  u16* wvT = (u16*)(ws + take((size_t)512 * 512 * 2));
  u16* woT = (u16*)(ws + take((size_t)512 * 512 * 2));
  u16* w1T = (u16*)(ws + take((size_t)512 * 2048 * 2));
  u16* w2T = (u16*)(ws + take((size_t)2048 * 512 * 2));
  float* hbuf = (float*)(ws + take((size_t)NTOK * ND * 4 + SLK));
  // qkv block: contiguous, one memset zeroes valid+pad regions
  const size_t QKV1 = (size_t)NB * NH * NLP * NDK * 2;  // 20.97 MB each
  u16* qb = (u16*)(ws + take(3 * QKV1 + SLK));
  u16* kb = qb + QKV1 / 2;
  u16* vt = kb + QKV1 / 2;
  u16* aog = (u16*)(ws + take((size_t)NTOK * ND * 2 + SLK));  // attn out, later ln2 out
  // region: xn (pre-attn) / u (FFN) — lifetimes disjoint
  size_t r7 = take((size_t)NTOK * NFF * 2 + SLK);
  u16* xn   = (u16*)(ws + r7);
  u16* ubuf = (u16*)(ws + r7);

  hipMemsetAsync(stats, 0, 512, stream);
  hipMemsetAsync(qb, 0, 3 * QKV1, stream);  // zero pads (rows/cols 577..639) for attn

  transpose_bf16<<<512, 256, 0, stream>>>(wq, wqT, 512, 512);
  transpose_bf16<<<512, 256, 0, stream>>>(wk, wkT, 512, 512);
  transpose_bf16<<<512, 256, 0, stream>>>(wv, wvT, 512, 512);
  transpose_bf16<<<512, 256, 0, stream>>>(wo, woT, 512, 512);
  transpose_bf16<<<2048, 256, 0, stream>>>(w1, w1T, 512, 2048);
  transpose_bf16<<<2048, 256, 0, stream>>>(w2, w2T, 2048, 512);

  // LN1 -> xn (bf16)
  ln_stats<<<dim3(NB, 8), 256, 0, stream>>>(x, stats1);
  ln_apply<<<2048, 256, 0, stream>>>(x, stats1, gamma1, beta1, xn);

  // Q,K,V projections (scattered into padded attn layouts)
  dim3 gP((NTOK + 127) / 128, ND / 128);
  gemm_bt<0><<<gP, 256, 0, stream>>>(xn, wqT, NTOK, ND, ND, ND, ND, bq, nullptr, 0, qb);
  gemm_bt<0><<<gP, 256, 0, stream>>>(xn, wkT, NTOK, ND, ND, ND, ND, bk, nullptr, 0, kb);
  gemm_bt<1><<<gP, 256, 0, stream>>>(xn, wvT, NTOK, ND, ND, ND, ND, bv, nullptr, 0, vt);

  // fused flash attention -> aog
  attn_fused<<<dim3(5, NB * NH), 256, 0, stream>>>(qb, kb, vt, aog);

  // output projection + residual(x) -> hbuf (f32)
  gemm_bt<4><<<gP, 256, 0, stream>>>(aog, woT, NTOK, ND, ND, ND, ND, bo, x, ND, hbuf);

  // LN2 -> g (bf16, reuses aog)
  ln_stats<<<dim3(NB, 8), 256, 0, stream>>>(hbuf, stats2);
  ln_apply<<<2048, 256, 0, stream>>>(hbuf, stats2, gamma2, beta2, aog);

  // FFN
  gemm_bt<5><<<dim3((NTOK + 127) / 128, NFF / 128), 256, 0, stream>>>(
      aog, w1T, NTOK, NFF, ND, ND, ND, b1, nullptr, 0, ubuf);
  gemm_bt<4><<<gP, 256, 0, stream>>>(ubuf, w2T, NTOK, ND, NFF, NFF, NFF, b2, hbuf, ND, out);
}

// Round 3
// 500.249 us; speedup vs baseline: 1.6179x; 1.0361x over previous
//
#include <hip/hip_runtime.h>
#include <math.h>

typedef unsigned short u16;
typedef __attribute__((ext_vector_type(8))) short short8;
typedef __attribute__((ext_vector_type(4))) float f32x4;
typedef __attribute__((ext_vector_type(16))) float f32x16;

constexpr int NB = 32, NL = 577, ND = 512, NH = 8, NDK = 64, NFF = 2048;
constexpr int NTOK = NB * NL;          // 18464 tokens
constexpr int NLP  = 640;              // L padded (Q rows and KV rows)
constexpr int LDN  = NL * ND;          // elements per batch (whole-seq LN)

__device__ __forceinline__ u16 f2bf(float f) {
  union { float f; unsigned u; } v; v.f = f;
  unsigned r = v.u + 0x7fffu + ((v.u >> 16) & 1u);   // round-nearest-even
  return (u16)(r >> 16);
}
__device__ __forceinline__ void gload_lds16(const void* g, void* l) {
  __builtin_amdgcn_global_load_lds((const __attribute__((address_space(1))) void*)g,
                                   (__attribute__((address_space(3))) void*)l, 16, 0, 0);
}
// bijective XCD swizzle (m204): consecutive output ids land on one XCD
__device__ __forceinline__ int xcd_swz(int lin, int nwg) {
  const int xcd = lin & 7, o = lin >> 3;
  const int q = nwg >> 3, r = nwg & 7;
  return (xcd < r ? xcd * (q + 1) : r * (q + 1) + (xcd - r) * q) + o;
}
__device__ __forceinline__ unsigned cvt_pk_bf16(float a, float b) {
  unsigned r;
  asm("v_cvt_pk_bf16_f32 %0, %1, %2" : "=v"(r) : "v"(a), "v"(b));
  return r;
}
__device__ __forceinline__ short8 mk8(unsigned a, unsigned b, unsigned c, unsigned d) {
  union { unsigned u[4]; short8 v; } f;
  f.u[0] = a; f.u[1] = b; f.u[2] = c; f.u[3] = d;
  return f.v;
}
__device__ __forceinline__ f32x16 mfma32(short8 a, short8 b, f32x16 c) {
  return __builtin_amdgcn_mfma_f32_32x32x16_bf16(a, b, c, 0, 0, 0);
}

// ---------------- whole-sequence LayerNorm ----------------
__global__ void ln_stats(const float* __restrict__ x, float* __restrict__ stats) {
  const int b = blockIdx.x, s = blockIdx.y;
  const int per4 = LDN / 8 / 4;
  const float4* xb = (const float4*)(x + (size_t)b * LDN + (size_t)s * (LDN / 8));
  float sum = 0.f, ss = 0.f;
  for (int i = threadIdx.x; i < per4; i += blockDim.x) {
    float4 v = xb[i];
    sum += v.x + v.y + v.z + v.w;
    ss  += v.x * v.x + v.y * v.y + v.z * v.z + v.w * v.w;
  }
#pragma unroll
  for (int o = 32; o; o >>= 1) { sum += __shfl_down(sum, o); ss += __shfl_down(ss, o); }
  __shared__ float s0[4], s1[4];
  const int lane = threadIdx.x & 63, w = threadIdx.x >> 6;
  if (lane == 0) { s0[w] = sum; s1[w] = ss; }
  __syncthreads();
  if (threadIdx.x == 0) {
    atomicAdd(&stats[b * 2 + 0], s0[0] + s0[1] + s0[2] + s0[3]);
    atomicAdd(&stats[b * 2 + 1], s1[0] + s1[1] + s1[2] + s1[3]);
  }
}

__global__ void ln_apply(const float* __restrict__ x, const float* __restrict__ stats,
                         const float* __restrict__ gamma, const float* __restrict__ beta,
                         u16* __restrict__ out) {
  const int nv = LDN / 4;
  const size_t total = (size_t)NB * nv;
  for (size_t i = (size_t)blockIdx.x * blockDim.x + threadIdx.x; i < total;
       i += (size_t)gridDim.x * blockDim.x) {
    const int b = (int)(i / nv);
    const int j = (int)(i - (size_t)b * nv);
    const float sum = stats[b * 2], ssum = stats[b * 2 + 1];
    const float mean = sum / (float)LDN;
    const float var = (ssum - (float)LDN * mean * mean) / (float)(LDN - 1);
    const float inv = 1.0f / (sqrtf(var) + 1e-6f);
    const float4 xv = ((const float4*)x)[i];
    const float4 gv = ((const float4*)gamma)[j];
    const float4 bv = ((const float4*)beta)[j];
    ushort4 o;
    o.x = f2bf(gv.x * ((xv.x - mean) * inv) + bv.x);
    o.y = f2bf(gv.y * ((xv.y - mean) * inv) + bv.y);
    o.z = f2bf(gv.z * ((xv.z - mean) * inv) + bv.z);
    o.w = f2bf(gv.w * ((xv.w - mean) * inv) + bv.w);
    ((ushort4*)out)[i] = o;
  }
}

// ---------------- weight transpose fp32[K][N] -> bf16[N][K] ----------------
__global__ void transpose_bf16(const float* __restrict__ w, u16* __restrict__ wt,
                               int K, int N) {
  const size_t total = (size_t)K * N;
  for (size_t i = (size_t)blockIdx.x * blockDim.x + threadIdx.x; i < total;
       i += (size_t)gridDim.x * blockDim.x) {
    const int k = (int)(i / N), n = (int)(i - (size_t)k * N);
    wt[(size_t)n * K + k] = f2bf(w[i]);
  }
}

// ---------------- generic bf16 MFMA GEMM: C = A[M,K] @ Bt[N,K]^T ----------------
// 128x128 tile, BK=32, 4 waves, global_load_lds w=16, XCD-chunked.
// EPI: 0 q/k scatter +bias, *oscale (pad-640 rows)  1 v scatter-transposed +bias
//      4 f32 out = v+bias+res                       5 bf16 out = gelu(v+bias)
template <int EPI>
__global__ __launch_bounds__(256, 2) void gemm_bt(
    const u16* __restrict__ A, const u16* __restrict__ Bt,
    int M, int N, int K, int lda, int ldb,
    const float* __restrict__ bias,
    const float* __restrict__ res, int ldr,
    void* __restrict__ outp, float oscale) {
  __shared__ __align__(16) u16 lA[128 * 32];
  __shared__ __align__(16) u16 lB[128 * 32];
  int lin = blockIdx.x + blockIdx.y * gridDim.x;
  lin = xcd_swz(lin, gridDim.x * gridDim.y);
  const int bx = lin / gridDim.y, by = lin - (lin / gridDim.y) * gridDim.y;
  const int m0 = bx * 128, n0 = by * 128;
  const int tid = threadIdx.x, lane = tid & 63, wid = tid >> 6;
  const int l16 = lane & 15, l4 = lane >> 4;
  const int wm = wid >> 1, wn = wid & 1;

  f32x4 acc[4][4] = {};

  const int e0 = wid * 1024 + lane * 8;
  for (int k0 = 0; k0 < K; k0 += 32) {
#pragma unroll
    for (int i = 0; i < 2; i++) {
      const int e = e0 + i * 512;
      const int row = e >> 5, kk = e & 31;
      gload_lds16(A + (size_t)(m0 + row) * lda + (k0 + kk), &lA[wid * 1024 + i * 512]);
      gload_lds16(Bt + (size_t)(n0 + row) * ldb + (k0 + kk), &lB[wid * 1024 + i * 512]);
    }
    __syncthreads();
    short8 af[4], bfr[4];
#pragma unroll
    for (int mi = 0; mi < 4; mi++)
      af[mi] = *(const short8*)&lA[(wm * 64 + mi * 16 + l16) * 32 + l4 * 8];
#pragma unroll
    for (int ni = 0; ni < 4; ni++)
      bfr[ni] = *(const short8*)&lB[(wn * 64 + ni * 16 + l16) * 32 + l4 * 8];
#pragma unroll
    for (int mi = 0; mi < 4; mi++)
#pragma unroll
      for (int ni = 0; ni < 4; ni++)
        acc[mi][ni] = __builtin_amdgcn_mfma_f32_16x16x32_bf16(af[mi], bfr[ni], acc[mi][ni], 0, 0, 0);
    __syncthreads();
  }

#pragma unroll
  for (int mi = 0; mi < 4; mi++) {
#pragma unroll
    for (int r = 0; r < 4; r++) {
      const int row = m0 + wm * 64 + mi * 16 + l4 * 4 + r;
      if (row >= M) continue;
      int rb = 0, rl = 0;
      if (EPI == 0 || EPI == 1) { rb = row / NL; rl = row - rb * NL; }
#pragma unroll
      for (int ni = 0; ni < 4; ni++) {
        const int col = n0 + wn * 64 + ni * 16 + l16;
        if (col >= N) continue;
        const float v = acc[mi][ni][r];
        if (EPI == 0) {          // q/k -> [BH][NLP][DK] bf16, rows 577..639 stay zero
          const int h = col >> 6, d = col & 63;
          ((u16*)outp)[(((size_t)rb * NH + h) * NLP + rl) * NDK + d] =
              f2bf((v + bias[col]) * oscale);
        } else if (EPI == 1) {   // v -> [BH][DK][NLP] bf16 (transposed, cols 577.. zero)
          const int h = col >> 6, d = col & 63;
          ((u16*)outp)[(((size_t)rb * NH + h) * NDK + d) * NLP + rl] = f2bf(v + bias[col]);
        } else if (EPI == 4) {   // f32 out = v + bias + residual
          ((float*)outp)[(size_t)row * N + col] = v + bias[col] + res[(size_t)row * ldr + col];
        } else {                 // 5: bf16 out = gelu(v + bias), tanh-form via exp
          const float t = v + bias[col];
          const float u = 0.7978845608028654f * t * (1.0f + 0.044715f * t * t);
          const float e = __expf(-2.0f * fabsf(u));
          float th = (1.0f - e) * __builtin_amdgcn_rcpf(1.0f + e);
          th = u < 0.f ? -th : th;
          ((u16*)outp)[(size_t)row * N + col] = f2bf(0.5f * t * (1.0f + th));
        }
      }
    }
  }
}

// ---------------- fused flash attention, swapped-QK in-register softmax ----------------
// 1-wave blocks; grid (20 q-tiles, 256 bh). 32x32x16 MFMA.
// S^T = mfma(K, Q): lane owns q-row (col=lane&31), kv = (reg&3)+8*(reg>>2)+4*hi.
// Softmax in f32 regs; P packed to bf16 via v_cvt_pk; cross-half via shfl_xor(32).
// PV: O^T = mfma(V^T, P^T) using vt [bh][d][kv]. Zero LDS.
__global__ __launch_bounds__(64, 3) void attn_fused(
    const u16* __restrict__ qb, const u16* __restrict__ kb,
    const u16* __restrict__ vt, u16* __restrict__ aog) {
  const int lane = threadIdx.x & 63;
  const int l32 = lane & 31, hi = lane >> 5;
  int lin = blockIdx.x + blockIdx.y * gridDim.x;
  lin = xcd_swz(lin, gridDim.x * gridDim.y);
  const int qt = lin % 20, bh = lin / 20;
  const int q0 = qt * 32;
  const u16* Qp = qb + (size_t)bh * NLP * NDK + (size_t)(q0 + l32) * NDK + hi * 8;
  const u16* Kp = kb + (size_t)bh * NLP * NDK + (size_t)l32 * NDK + hi * 8;
  const u16* Vp = vt + (size_t)bh * NDK * NLP + (size_t)l32 * NLP + hi * 8;

  short8 qf[4];
#pragma unroll
  for (int kc = 0; kc < 4; kc++) qf[kc] = *(const short8*)(Qp + kc * 16);

  f32x16 o0 = {}, o1 = {};
  float m = -3e38f, l = 0.f;

  for (int kv0 = 0; kv0 < NLP; kv0 += 64) {
    // ---- S^T for 64 kv (2 sub-tiles of 32) ----
    f32x16 s0 = {}, s1 = {};
#pragma unroll
    for (int kc = 0; kc < 4; kc++) {
      const short8 ka = *(const short8*)(Kp + (size_t)kv0 * NDK + kc * 16);
      const short8 kbf = *(const short8*)(Kp + (size_t)(kv0 + 32) * NDK + kc * 16);
      s0 = mfma32(ka, qf[kc], s0);
      s1 = mfma32(kbf, qf[kc], s1);
    }
    // ---- V fragments (prefetch; independent of softmax VALU) ----
    short8 vf0[4], vf1[4];
#pragma unroll
    for (int ks = 0; ks < 4; ks++) {
      vf0[ks] = *(const short8*)(Vp + (size_t)(kv0 + ks * 16));
      vf1[ks] = *(const short8*)(Vp + (size_t)32 * NLP + (kv0 + ks * 16));
    }
    // ---- tail mask (only last tile has kv >= 577) ----
    if (kv0 + 64 > NL) {
#pragma unroll
      for (int r = 0; r < 16; r++) {
        const int kvb = kv0 + (r & 3) + 8 * (r >> 2) + 4 * hi;
        s0[r] = (kvb < NL) ? s0[r] : -1e30f;
        s1[r] = (kvb + 32 < NL) ? s1[r] : -1e30f;
      }
    }
    // ---- online softmax, row fully lane-local (+1 cross-half hop) ----
    float t = -3e38f;
#pragma unroll
    for (int r = 0; r < 16; r++) t = fmaxf(t, fmaxf(s0[r], s1[r]));
    t = fmaxf(t, __shfl_xor(t, 32));
    if (!__all(t - m <= 8.0f)) {   // defer-max (T13): rescale only on real growth
      const float mn = fmaxf(m, t);
      const float sc = __expf(m - mn);
      m = mn;
      l *= sc;
#pragma unroll
      for (int r = 0; r < 16; r++) { o0[r] *= sc; o1[r] *= sc; }
    }
    float rs = 0.f;
#pragma unroll
    for (int r = 0; r < 16; r++) { s0[r] = __expf(s0[r] - m); rs += s0[r]; }
#pragma unroll
    for (int r = 0; r < 16; r++) { s1[r] = __expf(s1[r] - m); rs += s1[r]; }
    l += rs + __shfl_xor(rs, 32);

    // ---- pack P to bf16 words; build B-fragments via cross-half exchange ----
    unsigned w0[8], w1[8], p0[8], p1[8];
#pragma unroll
    for (int i = 0; i < 8; i++) {
      w0[i] = cvt_pk_bf16(s0[2 * i], s0[2 * i + 1]);
      w1[i] = cvt_pk_bf16(s1[2 * i], s1[2 * i + 1]);
    }
#pragma unroll
    for (int i = 0; i < 8; i++) {
      p0[i] = (unsigned)__shfl_xor((int)w0[i], 32);
      p1[i] = (unsigned)__shfl_xor((int)w1[i], 32);
    }
    short8 pa[4];
    pa[0] = mk8(hi ? p0[2] : w0[0], hi ? p0[3] : w0[1], hi ? w0[2] : p0[0], hi ? w0[3] : p0[1]);
    pa[1] = mk8(hi ? p0[6] : w0[4], hi ? p0[7] : w0[5], hi ? w0[6] : p0[4], hi ? w0[7] : p0[5]);
    pa[2] = mk8(hi ? p1[2] : w1[0], hi ? p1[3] : w1[1], hi ? w1[2] : p1[0], hi ? w1[3] : p1[1]);
    pa[3] = mk8(hi ? p1[6] : w1[4], hi ? p1[7] : w1[5], hi ? w1[6] : p1[4], hi ? w1[7] : p1[5]);
    // ---- O^T += V^T @ P^T ----
#pragma unroll
    for (int ks = 0; ks < 4; ks++) {
      o0 = mfma32(vf0[ks], pa[ks], o0);
      o1 = mfma32(vf1[ks], pa[ks], o1);
    }
  }

  // ---- normalize + store (lane owns q-row q0+l32; d from reg index) ----
  const int b = bh >> 3, h = bh & 7;
  const int qg = q0 + l32;
  if (qg < NL) {
    const float inv = 1.0f / l;
    u16* orow = aog + ((size_t)b * NL + qg) * ND + h * NDK;
#pragma unroll
    for (int r = 0; r < 16; r += 2) {
      const int d = (r & 3) + 4 * hi + 8 * (r >> 2);
      *(unsigned*)(orow + d) = cvt_pk_bf16(o0[r] * inv, o0[r + 1] * inv);
      *(unsigned*)(orow + 32 + d) = cvt_pk_bf16(o1[r] * inv, o1[r + 1] * inv);
    }
  }
}

extern "C" void kernel_launch(void* const* d_in, const int* in_sizes, int n_in,
                              void* d_out, int out_size, void* d_ws, size_t ws_size,
                              hipStream_t stream) {
  const float* x      = (const float*)d_in[0];
  const float* gamma1 = (const float*)d_in[1];
  const float* beta1  = (const float*)d_in[2];
  const float* gamma2 = (const float*)d_in[3];
  const float* beta2  = (const float*)d_in[4];
  const float* wq = (const float*)d_in[5];
  const float* bq = (const float*)d_in[6];
  const float* wk = (const float*)d_in[7];
  const float* bk = (const float*)d_in[8];
  const float* wv = (const float*)d_in[9];
  const float* bv = (const float*)d_in[10];
  const float* wo = (const float*)d_in[11];
  const float* bo = (const float*)d_in[12];
  const float* w1 = (const float*)d_in[13];
  const float* b1 = (const float*)d_in[14];
  const float* w2 = (const float*)d_in[15];
  const float* b2 = (const float*)d_in[16];
  float* out = (float*)d_out;

  char* ws = (char*)d_ws;
  size_t off = 0;
  auto take = [&](size_t bytes) { size_t o = off; off += (bytes + 255) & ~(size_t)255; return o; };
  const size_t SLK = 1u << 20;  // tail slack: edge tiles may over-read

  float* stats = (float*)(ws + take(512));
  float* stats1 = stats;
  float* stats2 = stats + 64;
  u16* wqT = (u16*)(ws + take((size_t)512 * 512 * 2));
  u16* wkT = (u16*)(ws + take((size_t)512 * 512 * 2));
  u16* wvT = (u16*)(ws + take((size_t)512 * 512 * 2));
  u16* woT = (u16*)(ws + take((size_t)512 * 512 * 2));
  u16* w1T = (u16*)(ws + take((size_t)512 * 2048 * 2));
  u16* w2T = (u16*)(ws + take((size_t)2048 * 512 * 2));
  float* hbuf = (float*)(ws + take((size_t)NTOK * ND * 4 + SLK));
  const size_t QKV1 = (size_t)NB * NH * NLP * NDK * 2;  // 21 MB each
  u16* qb = (u16*)(ws + take(3 * QKV1 + SLK));
  u16* kb = qb + QKV1 / 2;
  u16* vt = kb + QKV1 / 2;
  u16* aog = (u16*)(ws + take((size_t)NTOK * ND * 2 + SLK));  // attn out, later ln2 out
  size_t r7 = take((size_t)NTOK * NFF * 2 + SLK);
  u16* xn   = (u16*)(ws + r7);
  u16* ubuf = (u16*)(ws + r7);

  hipMemsetAsync(stats, 0, 512, stream);
  hipMemsetAsync(qb, 0, 3 * QKV1, stream);  // zero pads (rows/cols 577..639)

  transpose_bf16<<<512, 256, 0, stream>>>(wq, wqT, 512, 512);
  transpose_bf16<<<512, 256, 0, stream>>>(wk, wkT, 512, 512);
  transpose_bf16<<<512, 256, 0, stream>>>(wv, wvT, 512, 512);
  transpose_bf16<<<512, 256, 0, stream>>>(wo, woT, 512, 512);
  transpose_bf16<<<2048, 256, 0, stream>>>(w1, w1T, 512, 2048);
  transpose_bf16<<<2048, 256, 0, stream>>>(w2, w2T, 2048, 512);

  // LN1 -> xn (bf16)
  ln_stats<<<dim3(NB, 8), 256, 0, stream>>>(x, stats1);
  ln_apply<<<2048, 256, 0, stream>>>(x, stats1, gamma1, beta1, xn);

  // Q,K,V projections (scattered into padded attn layouts; 1/sqrt(512) folded into Q)
  dim3 gP((NTOK + 127) / 128, ND / 128);
  gemm_bt<0><<<gP, 256, 0, stream>>>(xn, wqT, NTOK, ND, ND, ND, ND, bq, nullptr, 0, qb,
                                     0.04419417382415922f);
  gemm_bt<0><<<gP, 256, 0, stream>>>(xn, wkT, NTOK, ND, ND, ND, ND, bk, nullptr, 0, kb, 1.0f);
  gemm_bt<1><<<gP, 256, 0, stream>>>(xn, wvT, NTOK, ND, ND, ND, ND, bv, nullptr, 0, vt, 1.0f);

  // fused flash attention -> aog
  attn_fused<<<dim3(20, NB * NH), 64, 0, stream>>>(qb, kb, vt, aog);

  // output projection + residual(x) -> hbuf (f32)
  gemm_bt<4><<<gP, 256, 0, stream>>>(aog, woT, NTOK, ND, ND, ND, ND, bo, x, ND, hbuf, 1.0f);

  // LN2 -> g (bf16, reuses aog)
  ln_stats<<<dim3(NB, 8), 256, 0, stream>>>(hbuf, stats2);
  ln_apply<<<2048, 256, 0, stream>>>(hbuf, stats2, gamma2, beta2, aog);

  // FFN
  gemm_bt<5><<<dim3((NTOK + 127) / 128, NFF / 128), 256, 0, stream>>>(
      aog, w1T, NTOK, NFF, ND, ND, ND, b1, nullptr, 0, ubuf, 1.0f);
  gemm_bt<4><<<gP, 256, 0, stream>>>(ubuf, w2T, NTOK, ND, NFF, NFF, NFF, b2, hbuf, ND, out, 1.0f);
}